// Round 1
// baseline (318.664 us; speedup 1.0000x reference)
//
#include <hip/hip_runtime.h>
#include <math.h>

#define BATCH 32
#define N 160
#define CH 3
#define LDIM 128
#define OUT 150          // N - 11 + 1
#define P 38             // (160-12)/4 + 1
#define FWIN 12

#define KLD_BLOCKS 16                          // 16*256 = 4096 = 32*128
#define SSIM_TOTAL (BATCH*CH*19*OUT)           // 273600 (19 strips of 8 rows)
#define SSIM_BLOCKS ((SSIM_TOTAL + 255) / 256) // 1069
#define STFT_TOTAL (BATCH*P*P*CH*5)            // 693120 (u = 1..5 only; u=0 has ff=0)
#define STFT_BLOCKS ((STFT_TOTAL + 255) / 256) // 2708
#define TOTAL_PARTIALS (KLD_BLOCKS + SSIM_BLOCKS + STFT_BLOCKS) // 3793

// thread-0-valid block sum over 256 threads (4 waves of 64)
__device__ __forceinline__ float block_sum(float v) {
    #pragma unroll
    for (int o = 32; o > 0; o >>= 1) v += __shfl_down(v, o, 64);
    __shared__ float sm[4];
    int w = threadIdx.x >> 6;
    if ((threadIdx.x & 63) == 0) sm[w] = v;
    __syncthreads();
    if (threadIdx.x == 0) v = sm[0] + sm[1] + sm[2] + sm[3];
    return v;
}

// ---------------- KLD ----------------
__global__ __launch_bounds__(256) void kld_kernel(const float* __restrict__ mean,
                                                  const float* __restrict__ logvar,
                                                  float* __restrict__ partial) {
    int idx = blockIdx.x * 256 + threadIdx.x;
    float a = 0.f;
    if (idx < BATCH * LDIM) {
        float m = mean[idx], lv = logvar[idx];
        // -0.5*(1 + lv - exp(lv) - m*m), then mean over batch (/32), BETA=1
        a = -0.5f * (1.f + lv - expf(lv) - m * m) * (1.f / 32.f);
    }
    float s = block_sum(a);
    if (threadIdx.x == 0) partial[blockIdx.x] = s;
}

// ---------------- SSIM ----------------
// thread = (b, c, strip of 8 output rows, output col v). Separable Gaussian:
// horizontal 11-tap per input row shared across up to 8 vertical outputs.
__global__ __launch_bounds__(256) void ssim_kernel(const float* __restrict__ xin,
                                                   const float* __restrict__ xout,
                                                   float* __restrict__ partial) {
    int idx = blockIdx.x * 256 + threadIdx.x;
    float acc = 0.f;
    if (idx < SSIM_TOTAL) {
        int v = idx % OUT; int t = idx / OUT;
        int s = t % 19; t /= 19;
        int c = t % 3; int b = t / 3;

        // normalized 1-D gaussian (size 11, sigma 1.5); outer(g,g)/sum == gn (x) gn
        float g[11]; float gsum = 0.f;
        #pragma unroll
        for (int i = 0; i < 11; ++i) {
            float d = (float)(i - 5) * (1.f / 1.5f);
            g[i] = expf(-0.5f * d * d);
            gsum += g[i];
        }
        float ginv = 1.f / gsum;
        #pragma unroll
        for (int i = 0; i < 11; ++i) g[i] *= ginv;

        int u0 = s * 8;
        float aX[8], aY[8], aXX[8], aYY[8], aXY[8];
        #pragma unroll
        for (int o = 0; o < 8; ++o) { aX[o]=0.f; aY[o]=0.f; aXX[o]=0.f; aYY[o]=0.f; aXY[o]=0.f; }

        #pragma unroll
        for (int rr = 0; rr < 18; ++rr) {
            int row = u0 + rr;
            if (row < N) {
                const float* px = xin  + (((size_t)b * N + row) * N + v) * CH + c;
                const float* py = xout + (((size_t)b * N + row) * N + v) * CH + c;
                float sx=0.f, sy=0.f, sxx=0.f, syy=0.f, sxy=0.f;
                #pragma unroll
                for (int tc = 0; tc < 11; ++tc) {
                    float xv = px[tc * CH], yv = py[tc * CH];
                    float w = g[tc];
                    sx  += w * xv;      sy  += w * yv;
                    sxx += w * xv * xv; syy += w * yv * yv;
                    sxy += w * xv * yv;
                }
                #pragma unroll
                for (int o = 0; o < 8; ++o) {
                    int d = rr - o;                // compile-time per (rr,o)
                    if (d >= 0 && d <= 10) {
                        float w = g[d];
                        aX[o]  += w * sx;  aY[o]  += w * sy;
                        aXX[o] += w * sxx; aYY[o] += w * syy;
                        aXY[o] += w * sxy;
                    }
                }
            }
        }
        const float c1 = 1e-4f, c2 = 9e-4f;
        float res = 0.f;
        #pragma unroll
        for (int o = 0; o < 8; ++o) {
            int u = u0 + o;
            if (u < OUT) {
                float mx = aX[o], my = aY[o];
                float vx = aXX[o] - mx * mx;
                float vy = aYY[o] - my * my;
                float cv = aXY[o] - mx * my;
                float lum = (2.f * mx * my + c1) / (mx * mx + my * my + c1);
                float cs  = (2.f * cv + c2) / (vx + vy + c2);
                res += lum * cs;
            }
        }
        acc = res * (1.f / (32.f * 150.f * 150.f * 3.f)); // SSIM_COEF=1, batch mean
    }
    float s2 = block_sum(acc);
    if (threadIdx.x == 0) partial[blockIdx.x] = s2;
}

// ---------------- STFT ----------------
// thread = (b, pr, pc, c, u) with u in 1..5; computes F[u, v] for v=1..5 for both
// images via separable DFT (row DFT shared across v with literal twiddles;
// column twiddle by rotation recurrence). ff[u][v] = u*v/25.
__global__ __launch_bounds__(256) void stft_kernel(const float* __restrict__ xin,
                                                   const float* __restrict__ xout,
                                                   float* __restrict__ partial) {
    int idx = blockIdx.x * 256 + threadIdx.x;
    float acc = 0.f;
    if (idx < STFT_TOTAL) {
        int t = idx;
        int u  = 1 + (t % 5); t /= 5;
        int c  = t % 3;       t /= 3;
        int pc = t % P;       t /= P;
        int pr = t % P;       int b = t / P;

        // e^{-i*2pi*k/12} = (cos(30k deg), -sin(30k deg)) — compile-time folded
        const float TWC[12] = { 1.f, 0.86602540f, 0.5f, 0.f, -0.5f, -0.86602540f,
                               -1.f,-0.86602540f,-0.5f, 0.f,  0.5f,  0.86602540f};
        const float TWS[12] = { 0.f,-0.5f,-0.86602540f,-1.f,-0.86602540f,-0.5f,
                                0.f, 0.5f, 0.86602540f, 1.f, 0.86602540f, 0.5f};

        float sb_s, cb_s;
        sincosf((float)u * 0.52359877559f, &sb_s, &cb_s);
        const float cb = cb_s, sb = -sb_s;   // e^{-i*2pi*u/12}

        float Fre[2][5], Fim[2][5];
        const float* bases[2];
        bases[0] = xin  + ((((size_t)b * N + (size_t)(pr * 4)) * N + (size_t)(pc * 4)) * CH) + c;
        bases[1] = xout + ((((size_t)b * N + (size_t)(pr * 4)) * N + (size_t)(pc * 4)) * CH) + c;

        #pragma unroll
        for (int img = 0; img < 2; ++img) {
            float fre[5] = {0,0,0,0,0}, fim[5] = {0,0,0,0,0};
            float cu = 1.f, su = 0.f;        // e^{-i*2pi*u*i/12}, i=0
            const float* base = bases[img];
            #pragma unroll
            for (int i = 0; i < 12; ++i) {
                const float* rowp = base + (size_t)i * (N * CH);
                float rre[5] = {0,0,0,0,0}, rim[5] = {0,0,0,0,0};
                #pragma unroll
                for (int j = 0; j < 12; ++j) {
                    float xv = rowp[j * CH];
                    #pragma unroll
                    for (int v = 1; v <= 5; ++v) {
                        int k = (v * j) % 12;          // compile-time
                        rre[v-1] += xv * TWC[k];
                        rim[v-1] += xv * TWS[k];
                    }
                }
                #pragma unroll
                for (int v = 0; v < 5; ++v) {
                    fre[v] += cu * rre[v] - su * rim[v];
                    fim[v] += cu * rim[v] + su * rre[v];
                }
                float cun = cu * cb - su * sb;         // rotate by e^{-i*2pi*u/12}
                float sun = cu * sb + su * cb;
                cu = cun; su = sun;
            }
            #pragma unroll
            for (int v = 0; v < 5; ++v) { Fre[img][v] = fre[v]; Fim[img][v] = fim[v]; }
        }

        float lsum = 0.f;
        #pragma unroll
        for (int v = 1; v <= 5; ++v) {
            float reI = Fre[0][v-1], imI = Fim[0][v-1];
            float reO = Fre[1][v-1], imO = Fim[1][v-1];
            float aI = atan2f(imI, reI + 1e-8f);
            float aO = atan2f(imO, reO + 1e-8f);
            float mI = sqrtf(reI * reI + imI * imI);
            float mO = sqrtf(reO * reO + imO * imO);
            float ff = (float)(u * v) * 0.04f;         // (u/5)*(v/5)
            lsum += ff * (fabsf(aO - aI) + fabsf(mO - mI));
        }
        acc = lsum * (1e-4f / 32.f);                   // STFT_COEF, batch mean
    }
    float s2 = block_sum(acc);
    if (threadIdx.x == 0) partial[blockIdx.x] = s2;
}

// ---------------- final reduce ----------------
__global__ __launch_bounds__(256) void final_kernel(const float* __restrict__ partial,
                                                    float* __restrict__ out) {
    float a = 0.f;
    for (int i = threadIdx.x; i < TOTAL_PARTIALS; i += 256) a += partial[i];
    float s = block_sum(a);
    if (threadIdx.x == 0) out[0] = s;
}

extern "C" void kernel_launch(void* const* d_in, const int* in_sizes, int n_in,
                              void* d_out, int out_size, void* d_ws, size_t ws_size,
                              hipStream_t stream) {
    const float* mean   = (const float*)d_in[0];
    const float* logvar = (const float*)d_in[1];
    const float* xin    = (const float*)d_in[2];
    const float* xout   = (const float*)d_in[3];
    float* out = (float*)d_out;
    float* partial = (float*)d_ws;

    kld_kernel <<<KLD_BLOCKS, 256, 0, stream>>>(mean, logvar, partial);
    ssim_kernel<<<SSIM_BLOCKS, 256, 0, stream>>>(xin, xout, partial + KLD_BLOCKS);
    stft_kernel<<<STFT_BLOCKS, 256, 0, stream>>>(xin, xout, partial + KLD_BLOCKS + SSIM_BLOCKS);
    final_kernel<<<1, 256, 0, stream>>>(partial, out);
}

// Round 2
// 183.958 us; speedup vs baseline: 1.7323x; 1.7323x over previous
//
#include <hip/hip_runtime.h>
#include <math.h>

#define BATCH 32
#define N 160
#define CH 3
#define LDIM 128
#define OUT 150          // N - 11 + 1
#define P 38             // (160-12)/4 + 1

#define SSIM_TILES 19                          // ceil(150/8)
#define SSIM_BLOCKS (BATCH*CH*SSIM_TILES)      // 1824
#define STFT_BLOCKS (BATCH*CH*P)               // 3648
#define TOTAL_PARTIALS (SSIM_BLOCKS + STFT_BLOCKS) // 5472

// thread-0-valid block sum over 256 threads (4 waves of 64)
__device__ __forceinline__ float block_sum(float v) {
    #pragma unroll
    for (int o = 32; o > 0; o >>= 1) v += __shfl_down(v, o, 64);
    __shared__ float sm[4];
    int w = threadIdx.x >> 6;
    if ((threadIdx.x & 63) == 0) sm[w] = v;
    __syncthreads();
    if (threadIdx.x == 0) v = sm[0] + sm[1] + sm[2] + sm[3];
    return v;
}

// ---------------- SSIM ----------------
// block = (tile of 8 output rows, c, b). Separable gaussian via LDS:
// phase1 stage 18 input rows, phase2 vertical 11-tap -> 5 stat planes,
// phase3 horizontal 11-tap + SSIM formula.
__global__ __launch_bounds__(256) void ssim_kernel(const float* __restrict__ xin,
                                                   const float* __restrict__ xout,
                                                   float* __restrict__ partial) {
    __shared__ float sx[18 * 160];
    __shared__ float sy[18 * 160];
    __shared__ float Vx[8 * 160], Vy[8 * 160], Vxx[8 * 160], Vyy[8 * 160], Vxy[8 * 160];

    const int tile = blockIdx.x, c = blockIdx.y, b = blockIdx.z;
    const int tid = threadIdx.x;
    const int r0 = tile * 8;

    // normalized 1-D gaussian, computed once (matches reference bit-pattern closely)
    float g[11];
    {
        float gsum = 0.f;
        #pragma unroll
        for (int i = 0; i < 11; ++i) {
            float d = (float)(i - 5) * (1.f / 1.5f);
            g[i] = expf(-0.5f * d * d);
            gsum += g[i];
        }
        float ginv = 1.f / gsum;
        #pragma unroll
        for (int i = 0; i < 11; ++i) g[i] *= ginv;
    }

    // phase 1: stage input rows r0 .. r0+17 (guard bottom tile)
    for (int i = tid; i < 18 * 160; i += 256) {
        int r = i / 160, col = i % 160;
        int row = r0 + r;
        float vx = 0.f, vy = 0.f;
        if (row < N) {
            size_t off = (((size_t)b * N + row) * N + col) * CH + c;
            vx = xin[off];
            vy = xout[off];
        }
        sx[i] = vx; sy[i] = vy;
    }
    __syncthreads();

    // phase 2: vertical 11-tap -> V planes [8][160]
    for (int i = tid; i < 8 * 160; i += 256) {
        int orow = i / 160, col = i % 160;
        float ax = 0.f, ay = 0.f, axx = 0.f, ayy = 0.f, axy = 0.f;
        #pragma unroll
        for (int k = 0; k < 11; ++k) {
            float xv = sx[(orow + k) * 160 + col];
            float yv = sy[(orow + k) * 160 + col];
            float w = g[k];
            ax  += w * xv;       ay  += w * yv;
            axx += w * (xv * xv); ayy += w * (yv * yv);
            axy += w * (xv * yv);
        }
        Vx[i] = ax; Vy[i] = ay; Vxx[i] = axx; Vyy[i] = ayy; Vxy[i] = axy;
    }
    __syncthreads();

    // phase 3: horizontal 11-tap + SSIM
    float acc = 0.f;
    for (int i = tid; i < 8 * OUT; i += 256) {
        int orow = i / OUT, oc = i % OUT;
        if (r0 + orow < OUT) {
            float mx = 0.f, my = 0.f, sxx = 0.f, syy = 0.f, sxy = 0.f;
            #pragma unroll
            for (int k = 0; k < 11; ++k) {
                float w = g[k];
                int idx = orow * 160 + oc + k;
                mx  += w * Vx[idx];  my  += w * Vy[idx];
                sxx += w * Vxx[idx]; syy += w * Vyy[idx];
                sxy += w * Vxy[idx];
            }
            float vx = sxx - mx * mx;
            float vy = syy - my * my;
            float cv = sxy - mx * my;
            const float c1 = 1e-4f, c2 = 9e-4f;
            float lum = (2.f * mx * my + c1) / (mx * mx + my * my + c1);
            float cs  = (2.f * cv + c2) / (vx + vy + c2);
            acc += lum * cs;
        }
    }
    acc *= 1.f / (32.f * 150.f * 150.f * 3.f); // batch mean + spatial mean, SSIM_COEF=1
    float s = block_sum(acc);
    if (tid == 0) partial[blockIdx.x + SSIM_TILES * (blockIdx.y + CH * blockIdx.z)] = s;
}

// ---------------- STFT ----------------
// block = (pr, c, b). phase1 stage 12 image rows x 160 cols x 2 imgs into LDS;
// phase2 row DFT once per (img, i, pc) -> RD[img][i][pc][v(re,im)]; phase3
// column DFT per (pc, u, v) + angle/abs loss.
__global__ __launch_bounds__(256) void stft_kernel(const float* __restrict__ xin,
                                                   const float* __restrict__ xout,
                                                   float* __restrict__ partial) {
    __shared__ __align__(16) float rows[2 * 12 * 160];  // [img][i][col]
    __shared__ __align__(16) float RD[2 * 12 * 38 * 10]; // [img][i][pc][2*(v-1)+{re,im}]

    const int pr = blockIdx.x, c = blockIdx.y, b = blockIdx.z;
    const int tid = threadIdx.x;
    const int rbase = pr * 4;

    // phase 1: stage rows (contiguous cols, stride-CH in global)
    for (int i = tid; i < 2 * 12 * 160; i += 256) {
        int img = i / (12 * 160);
        int rem = i % (12 * 160);
        int r = rem / 160, col = rem % 160;
        const float* src = img ? xout : xin;
        rows[i] = src[(((size_t)b * N + rbase + r) * N + col) * CH + c];
    }
    __syncthreads();

    // e^{-i*2pi*k/12}
    const float TWC[12] = { 1.f, 0.86602540f, 0.5f, 0.f, -0.5f, -0.86602540f,
                           -1.f,-0.86602540f,-0.5f, 0.f,  0.5f,  0.86602540f};
    const float TWS[12] = { 0.f,-0.5f,-0.86602540f,-1.f,-0.86602540f,-0.5f,
                            0.f, 0.5f, 0.86602540f, 1.f, 0.86602540f, 0.5f};

    // phase 2: row DFTs, 912 tasks = (img, i, pc)
    for (int t = tid; t < 2 * 12 * 38; t += 256) {
        int pc = t % 38;
        int rem = t / 38;
        int i = rem % 12, img = rem / 12;
        const float4* rp = (const float4*)&rows[(img * 12 + i) * 160 + pc * 4];
        float4 q0 = rp[0], q1 = rp[1], q2 = rp[2];
        float x[12] = {q0.x,q0.y,q0.z,q0.w, q1.x,q1.y,q1.z,q1.w, q2.x,q2.y,q2.z,q2.w};
        float rre[5] = {0,0,0,0,0}, rim[5] = {0,0,0,0,0};
        #pragma unroll
        for (int j = 0; j < 12; ++j) {
            #pragma unroll
            for (int v = 1; v <= 5; ++v) {
                int k = (v * j) % 12;     // compile-time
                rre[v-1] += x[j] * TWC[k];
                rim[v-1] += x[j] * TWS[k];
            }
        }
        float2* wp = (float2*)&RD[((img * 12 + i) * 38 + pc) * 10];
        wp[0] = make_float2(rre[0], rim[0]);
        wp[1] = make_float2(rre[1], rim[1]);
        wp[2] = make_float2(rre[2], rim[2]);
        wp[3] = make_float2(rre[3], rim[3]);
        wp[4] = make_float2(rre[4], rim[4]);
    }
    __syncthreads();

    // phase 3: column DFT + loss, 950 tasks = (pc, u, v), u,v in 1..5
    float acc = 0.f;
    for (int t = tid; t < 38 * 25; t += 256) {
        int vv = t % 5;
        int uu = (t / 5) % 5;
        int pc = t / 25;
        int u = uu + 1, v = vv + 1;

        float sb_, cb_;
        sincosf((float)u * 0.52359877559f, &sb_, &cb_);
        const float cb = cb_, sb = -sb_;    // e^{-i*2pi*u/12}
        float cu = 1.f, su = 0.f;
        float fre0 = 0.f, fim0 = 0.f, fre1 = 0.f, fim1 = 0.f;
        #pragma unroll
        for (int i = 0; i < 12; ++i) {
            const float2 a  = *(const float2*)&RD[((0 * 12 + i) * 38 + pc) * 10 + 2 * vv];
            const float2 bb = *(const float2*)&RD[((1 * 12 + i) * 38 + pc) * 10 + 2 * vv];
            fre0 += cu * a.x  - su * a.y;   fim0 += cu * a.y  + su * a.x;
            fre1 += cu * bb.x - su * bb.y;  fim1 += cu * bb.y + su * bb.x;
            float cn = cu * cb - su * sb;
            float sn = cu * sb + su * cb;
            cu = cn; su = sn;
        }
        float aI = atan2f(fim0, fre0 + 1e-8f);
        float aO = atan2f(fim1, fre1 + 1e-8f);
        float mI = sqrtf(fre0 * fre0 + fim0 * fim0);
        float mO = sqrtf(fre1 * fre1 + fim1 * fim1);
        float ff = (float)(u * v) * 0.04f;   // (u/5)*(v/5)
        acc += ff * (fabsf(aO - aI) + fabsf(mO - mI));
    }
    acc *= 1e-4f / 32.f;                     // STFT_COEF, batch mean
    float s = block_sum(acc);
    if (tid == 0) partial[SSIM_BLOCKS + blockIdx.x + P * (blockIdx.y + CH * blockIdx.z)] = s;
}

// ---------------- final reduce (+ KLD inline) ----------------
__global__ __launch_bounds__(256) void final_kernel(const float* __restrict__ mean,
                                                    const float* __restrict__ logvar,
                                                    const float* __restrict__ partial,
                                                    float* __restrict__ out) {
    float a = 0.f;
    for (int i = threadIdx.x; i < BATCH * LDIM; i += 256) {
        float m = mean[i], lv = logvar[i];
        a += -0.5f * (1.f + lv - expf(lv) - m * m) * (1.f / 32.f);
    }
    for (int i = threadIdx.x; i < TOTAL_PARTIALS; i += 256) a += partial[i];
    float s = block_sum(a);
    if (threadIdx.x == 0) out[0] = s;
}

extern "C" void kernel_launch(void* const* d_in, const int* in_sizes, int n_in,
                              void* d_out, int out_size, void* d_ws, size_t ws_size,
                              hipStream_t stream) {
    const float* mean   = (const float*)d_in[0];
    const float* logvar = (const float*)d_in[1];
    const float* xin    = (const float*)d_in[2];
    const float* xout   = (const float*)d_in[3];
    float* out = (float*)d_out;
    float* partial = (float*)d_ws;

    ssim_kernel<<<dim3(SSIM_TILES, CH, BATCH), 256, 0, stream>>>(xin, xout, partial);
    stft_kernel<<<dim3(P, CH, BATCH), 256, 0, stream>>>(xin, xout, partial);
    final_kernel<<<1, 256, 0, stream>>>(mean, logvar, partial, out);
}